// Round 1
// baseline (85.099 us; speedup 1.0000x reference)
//
#include <hip/hip_runtime.h>
#include <math.h>

// ANI-style AEV: M=256 molecules, A=24 atoms, 4 species.
// Output per (m,i): 64 radial (s*16+r) then 320 angular (p*32 + a*8 + z).
// One 64-thread (1-wave) block per center (m,i).

#define AATOMS 24
#define NPAIRS_JK 276   // 24*23/2

__device__ __forceinline__ void decode_pair(int P, int& j, int& k) {
    // j = max { j : S(j) = j*(47-j)/2 <= P }, k = j+1 + (P - S(j))
    float f = sqrtf(2209.0f - 8.0f * (float)P);
    int jj = (int)((47.0f - f) * 0.5f);
    while (jj > 0 && (jj * (47 - jj)) / 2 > P) --jj;
    while (((jj + 1) * (47 - (jj + 1))) / 2 <= P) ++jj;
    j = jj;
    k = P - (jj * (47 - jj)) / 2 + jj + 1;
}

__global__ __launch_bounds__(64)
void aev_kernel(const int* __restrict__ species,
                const float* __restrict__ coords,
                float* __restrict__ out) {
    const int blk  = blockIdx.x;            // m*24 + i
    const int m    = blk / AATOMS;
    const int i    = blk - m * AATOMS;
    const int lane = threadIdx.x;           // 0..63 (one wave)

    __shared__ float s_acc[384];
    __shared__ float s_x[AATOMS], s_y[AATOMS], s_z[AATOMS];
    __shared__ float s_ux[AATOMS], s_uy[AATOMS], s_uz[AATOMS];
    __shared__ float s_dist[AATOMS], s_fca[AATOMS], s_fcr[AATOMS];
    __shared__ int   s_spec[AATOMS];
    __shared__ int   s_active[NPAIRS_JK];
    __shared__ int   s_count;

    // ---- phase 0: zero accumulators, load coords/species ----
    #pragma unroll
    for (int t = 0; t < 6; ++t) s_acc[lane + t * 64] = 0.0f;
    if (lane == 0) s_count = 0;
    if (lane < AATOMS) {
        const float* cp = coords + (m * AATOMS + lane) * 3;
        s_x[lane] = cp[0];
        s_y[lane] = cp[1];
        s_z[lane] = cp[2];
        s_spec[lane] = species[m * AATOMS + lane];
    }
    __syncthreads();

    // ---- phase 1: per-neighbor distance / cutoff / unit vectors ----
    if (lane < AATOMS) {
        const int j = lane;
        float dx = s_x[j] - s_x[i];
        float dy = s_y[j] - s_y[i];
        float dz = s_z[j] - s_z[i];
        float d2 = dx * dx + dy * dy + dz * dz;
        bool ok = (j != i);
        float d = ok ? sqrtf(d2) : 1.0f;
        float inv = 1.0f / d;
        float fcr = (ok && d <= 5.2f) ? fmaf(0.5f, __cosf(d * 0.6041524f), 0.5f) : 0.0f;
        float fca = (ok && d <= 3.5f) ? fmaf(0.5f, __cosf(d * 0.8975979f), 0.5f) : 0.0f;
        s_dist[j] = d;
        s_fcr[j] = fcr;
        s_fca[j] = fca;
        s_ux[j] = dx * inv;
        s_uy[j] = dy * inv;
        s_uz[j] = dz * inv;
    }
    __syncthreads();

    // ---- phase 2: radial AEV. lane -> (r = lane&15, group g = lane>>4). ----
    {
        const int r = lane & 15;
        const int g = lane >> 4;
        const float shf = 0.9f + 0.26875f * (float)r;
        float r0 = 0.f, r1 = 0.f, r2 = 0.f, r3 = 0.f;
        #pragma unroll
        for (int jj = 0; jj < 6; ++jj) {
            int j = g + jj * 4;
            float fcr = s_fcr[j];
            float t = s_dist[j] - shf;
            float v = 0.25f * __expf(-16.0f * t * t) * fcr;
            int sp = s_spec[j];
            r0 += (sp == 0) ? v : 0.0f;
            r1 += (sp == 1) ? v : 0.0f;
            r2 += (sp == 2) ? v : 0.0f;
            r3 += (sp == 3) ? v : 0.0f;
        }
        // reduce over g (lane bits 4 and 5)
        r0 += __shfl_xor(r0, 16); r0 += __shfl_xor(r0, 32);
        r1 += __shfl_xor(r1, 16); r1 += __shfl_xor(r1, 32);
        r2 += __shfl_xor(r2, 16); r2 += __shfl_xor(r2, 32);
        r3 += __shfl_xor(r3, 16); r3 += __shfl_xor(r3, 32);
        if (lane < 16) {
            s_acc[ 0 + lane] = r0;
            s_acc[16 + lane] = r1;
            s_acc[32 + lane] = r2;
            s_acc[48 + lane] = r3;
        }
    }

    // ---- phase 3: compact active (j,k) pairs (both inside RCA of i) ----
    for (int P = lane; P < NPAIRS_JK; P += 64) {
        int j, k;
        decode_pair(P, j, k);
        if (s_fca[j] > 0.0f && s_fca[k] > 0.0f) {
            int pos = atomicAdd(&s_count, 1);
            s_active[pos] = (j << 5) | k;
        }
    }
    __syncthreads();
    const int nact = s_count;

    // ---- phase 4: angular AEV over active pairs ----
    // Lane-rotated subfeature order: z rotated by (lane&7), a by ((lane>>3)&3)
    // -> across each half-wave all 32 ds_add_f32 addresses hit distinct banks.
    const int zrot = lane & 7;
    const int arot = (lane >> 3) & 3;
    float czr[8], szr[8];
    int   zr[8];
    #pragma unroll
    for (int t = 0; t < 8; ++t) {
        int z = (t + zrot) & 7;
        zr[t] = z;
        float ang = ((float)z + 0.5f) * 0.39269908f;   // (z+0.5)*pi/8
        czr[t] = 0.5f * __cosf(ang);
        szr[t] = 0.5f * __sinf(ang);
    }
    float sha[4];
    int   aoff[4];
    #pragma unroll
    for (int u = 0; u < 4; ++u) {
        int a = (u + arot) & 3;
        sha[u] = 0.9f + 0.65f * (float)a;
        aoff[u] = a * 8;
    }

    for (int it = lane; it < nact; it += 64) {
        int jk = s_active[it];
        int j = jk >> 5, k = jk & 31;
        float fj = s_fca[j], fk = s_fca[k];
        float w2 = 2.0f * fj * fk;
        float cosang = 0.95f * (s_ux[j] * s_ux[k] + s_uy[j] * s_uy[k] + s_uz[j] * s_uz[k]);
        float sinang = sqrtf(fmaxf(1.0f - cosang * cosang, 0.0f));
        float davg = 0.5f * (s_dist[j] + s_dist[k]);
        int sj = s_spec[j], sk = s_spec[k];
        int sa = min(sj, sk), sb = max(sj, sk);
        int p = sb + ((sa * (7 - sa)) >> 1);           // TRIU pair index
        float* accp = &s_acc[64 + p * 32];

        float wf2[4];
        #pragma unroll
        for (int u = 0; u < 4; ++u) {
            float t = davg - sha[u];
            wf2[u] = w2 * __expf(-8.0f * t * t);
        }
        float f1[8];
        #pragma unroll
        for (int t = 0; t < 8; ++t) {
            float c = fmaf(cosang, czr[t], fmaf(sinang, szr[t], 0.5f));
            float c2 = c * c, c4 = c2 * c2, c8 = c4 * c4, c16 = c8 * c8;
            f1[t] = c16 * c16;                          // c^32
        }
        #pragma unroll
        for (int u = 0; u < 4; ++u) {
            float wa = wf2[u];
            float* ap = accp + aoff[u];
            #pragma unroll
            for (int t = 0; t < 8; ++t) {
                atomicAdd(&ap[zr[t]], wa * f1[t]);
            }
        }
    }
    __syncthreads();

    // ---- phase 5: write out 384 features, coalesced ----
    float* op = out + blk * 384;
    #pragma unroll
    for (int t = 0; t < 6; ++t) op[lane + t * 64] = s_acc[lane + t * 64];
}

extern "C" void kernel_launch(void* const* d_in, const int* in_sizes, int n_in,
                              void* d_out, int out_size, void* d_ws, size_t ws_size,
                              hipStream_t stream) {
    const int*   species = (const int*)d_in[0];
    const float* coords  = (const float*)d_in[1];
    // d_in[2] (coefficients) is unused by the reference output.
    float* out = (float*)d_out;
    const int M = in_sizes[0] / AATOMS;
    aev_kernel<<<M * AATOMS, 64, 0, stream>>>(species, coords, out);
}

// Round 2
// 82.825 us; speedup vs baseline: 1.0274x; 1.0274x over previous
//
#include <hip/hip_runtime.h>
#include <math.h>

// ANI-style AEV: M=256 molecules, A=24 atoms, 4 species.
// Output per (m,i): 64 radial (s*16+r) then 320 angular (p*32 + a*8 + z).
// One 64-thread (1-wave) block per center (m,i).
//
// R1 changes vs R0:
//  - pair compaction via __ballot neighbor mask + popcount prefix (no shared
//    atomics, no 276-candidate scan with divergent decode loops)
//  - pairs enumerated directly from the (typically ~6-element) neighbor list
//  - barrier count cut from 4+ to 2 (geometry||ballot -> {radial, angular} -> out)

#define AATOMS 24

__global__ __launch_bounds__(64)
void aev_kernel(const int* __restrict__ species,
                const float* __restrict__ coords,
                float* __restrict__ out) {
    const int blk  = blockIdx.x;            // m*24 + i
    const int m    = blk / AATOMS;
    const int i    = blk - m * AATOMS;
    const int lane = threadIdx.x;           // 0..63 (one wave)

    __shared__ float s_acc[384];
    __shared__ float s_ux[AATOMS], s_uy[AATOMS], s_uz[AATOMS];
    __shared__ float s_dist[AATOMS], s_fca[AATOMS], s_fcr[AATOMS];
    __shared__ int   s_spec[AATOMS];
    __shared__ int   s_list[AATOMS];        // compacted neighbor list (d<=RCA)

    // ---- phase 0+1: zero accumulators; per-neighbor geometry; ballot ----
    #pragma unroll
    for (int t = 0; t < 6; ++t) s_acc[lane + t * 64] = 0.0f;

    bool active = false;
    if (lane < AATOMS) {
        const float* cb = coords + m * AATOMS * 3;
        float xi = cb[i * 3 + 0], yi = cb[i * 3 + 1], zi = cb[i * 3 + 2];
        float dx = cb[lane * 3 + 0] - xi;
        float dy = cb[lane * 3 + 1] - yi;
        float dz = cb[lane * 3 + 2] - zi;
        float d2 = dx * dx + dy * dy + dz * dz;
        bool ok = (lane != i);
        float d = ok ? sqrtf(d2) : 1.0f;
        float inv = 1.0f / d;
        float fcr = (ok && d <= 5.2f) ? fmaf(0.5f, __cosf(d * 0.6041524f), 0.5f) : 0.0f;
        float fca = (ok && d <= 3.5f) ? fmaf(0.5f, __cosf(d * 0.8975979f), 0.5f) : 0.0f;
        s_dist[lane] = d;
        s_fcr[lane] = fcr;
        s_fca[lane] = fca;
        s_ux[lane] = dx * inv;
        s_uy[lane] = dy * inv;
        s_uz[lane] = dz * inv;
        s_spec[lane] = species[m * AATOMS + lane];
        active = ok && (d <= 3.5f);
    }
    unsigned long long mask = __ballot(active);
    const int n = __popcll(mask);
    if (active) {
        int pos = __popcll(mask & ((1ull << lane) - 1ull));
        s_list[pos] = lane;
    }
    __syncthreads();

    // ---- phase 2: radial AEV. lane -> (r = lane&15, group g = lane>>4). ----
    {
        const int r = lane & 15;
        const int g = lane >> 4;
        const float shf = 0.9f + 0.26875f * (float)r;
        float r0 = 0.f, r1 = 0.f, r2 = 0.f, r3 = 0.f;
        #pragma unroll
        for (int jj = 0; jj < 6; ++jj) {
            int j = g + jj * 4;
            float fcr = s_fcr[j];
            float t = s_dist[j] - shf;
            float v = 0.25f * __expf(-16.0f * t * t) * fcr;
            int sp = s_spec[j];
            r0 += (sp == 0) ? v : 0.0f;
            r1 += (sp == 1) ? v : 0.0f;
            r2 += (sp == 2) ? v : 0.0f;
            r3 += (sp == 3) ? v : 0.0f;
        }
        r0 += __shfl_xor(r0, 16); r0 += __shfl_xor(r0, 32);
        r1 += __shfl_xor(r1, 16); r1 += __shfl_xor(r1, 32);
        r2 += __shfl_xor(r2, 16); r2 += __shfl_xor(r2, 32);
        r3 += __shfl_xor(r3, 16); r3 += __shfl_xor(r3, 32);
        if (lane < 16) {
            s_acc[ 0 + lane] = r0;
            s_acc[16 + lane] = r1;
            s_acc[32 + lane] = r2;
            s_acc[48 + lane] = r3;
        }
    }

    // ---- phase 3: angular AEV over pairs from the neighbor list ----
    // Lane-rotated subfeature order: z rotated by (lane&7), a by ((lane>>3)&3)
    // -> across each half-wave all 32 ds_add_f32 addresses hit distinct banks.
    const int zrot = lane & 7;
    const int arot = (lane >> 3) & 3;
    float czr[8], szr[8];
    int   zr[8];
    #pragma unroll
    for (int t = 0; t < 8; ++t) {
        int z = (t + zrot) & 7;
        zr[t] = z;
        float ang = ((float)z + 0.5f) * 0.39269908f;   // (z+0.5)*pi/8
        czr[t] = 0.5f * __cosf(ang);
        szr[t] = 0.5f * __sinf(ang);
    }
    float sha[4];
    int   aoff[4];
    #pragma unroll
    for (int u = 0; u < 4; ++u) {
        int a = (u + arot) & 3;
        sha[u] = 0.9f + 0.65f * (float)a;
        aoff[u] = a * 8;
    }

    const int npairs = (n * (n - 1)) >> 1;
    for (int q = lane; q < npairs; q += 64) {
        // decode q -> (a,b), a<b in [0,n): small loop, n is typically ~6
        int rem = q, a = 0, cnt = n - 1;
        while (rem >= cnt) { rem -= cnt; --cnt; ++a; }
        int b = a + 1 + rem;
        int j = s_list[a], k = s_list[b];

        float fj = s_fca[j], fk = s_fca[k];
        float w2 = 2.0f * fj * fk;
        float cosang = 0.95f * (s_ux[j] * s_ux[k] + s_uy[j] * s_uy[k] + s_uz[j] * s_uz[k]);
        float sinang = sqrtf(fmaxf(1.0f - cosang * cosang, 0.0f));
        float davg = 0.5f * (s_dist[j] + s_dist[k]);
        int sj = s_spec[j], sk = s_spec[k];
        int sa = min(sj, sk), sb = max(sj, sk);
        int p = sb + ((sa * (7 - sa)) >> 1);           // TRIU pair index
        float* accp = &s_acc[64 + p * 32];

        float wf2[4];
        #pragma unroll
        for (int u = 0; u < 4; ++u) {
            float t = davg - sha[u];
            wf2[u] = w2 * __expf(-8.0f * t * t);
        }
        float f1[8];
        #pragma unroll
        for (int t = 0; t < 8; ++t) {
            float c = fmaf(cosang, czr[t], fmaf(sinang, szr[t], 0.5f));
            float c2 = c * c, c4 = c2 * c2, c8 = c4 * c4, c16 = c8 * c8;
            f1[t] = c16 * c16;                          // c^32
        }
        #pragma unroll
        for (int u = 0; u < 4; ++u) {
            float wa = wf2[u];
            float* ap = accp + aoff[u];
            #pragma unroll
            for (int t = 0; t < 8; ++t) {
                atomicAdd(&ap[zr[t]], wa * f1[t]);
            }
        }
    }
    __syncthreads();

    // ---- phase 4: write out 384 features, coalesced ----
    float* op = out + blk * 384;
    #pragma unroll
    for (int t = 0; t < 6; ++t) op[lane + t * 64] = s_acc[lane + t * 64];
}

extern "C" void kernel_launch(void* const* d_in, const int* in_sizes, int n_in,
                              void* d_out, int out_size, void* d_ws, size_t ws_size,
                              hipStream_t stream) {
    const int*   species = (const int*)d_in[0];
    const float* coords  = (const float*)d_in[1];
    // d_in[2] (coefficients) is unused by the reference output.
    float* out = (float*)d_out;
    const int M = in_sizes[0] / AATOMS;
    aev_kernel<<<M * AATOMS, 64, 0, stream>>>(species, coords, out);
}